// Round 2
// baseline (747.412 us; speedup 1.0000x reference)
//
#include <hip/hip_runtime.h>

#define N_NODES 50000
#define N_EDGES 800000
#define D 64
#define ET_PAD 68   // node_pre LDS padding
#define NB 196      // ceil(50000/256) scan blocks

typedef __attribute__((ext_vector_type(8))) short short8;
typedef __attribute__((ext_vector_type(4))) float f32x4;

__device__ inline unsigned short f2bf(float f) {
    unsigned u = __float_as_uint(f);
    unsigned r = (u + 0x7FFFu + ((u >> 16) & 1u)) >> 16;
    return (unsigned short)r;
}

// ---------------------------------------------------------------------------
// Weight folding.
// Wbig[128][256] fp32 for node_pre GEMM [S|X]@Wbig:
//   cols 0..63 [Wv1;Wv2]->hbase, 64..127 [0;W_n2e_u@Ebot]->a,
//   128..191 [W_n2e_v@Ebot]->b, 192..255 [0;W_n2n_u@Wv3]->XC
// WTbf[128][64] bf16, B^T layout for the edge MFMA GEMM:
//   WTbf[n][k] = w_e2e[k][n] (n<64, ->e_out part), = WD[k][n-64] (n>=64, ->seg-sum part)
//   where WD = W_e2n@Wv3.  Ebot = w_e2e rows 64..127, Wv3 = w_n2n_v rows 128..191.
// ---------------------------------------------------------------------------
__global__ void fold_weights(const float* __restrict__ w_n2n_u,
                             const float* __restrict__ w_n2n_v,
                             const float* __restrict__ w_e2n,
                             const float* __restrict__ w_n2e_u,
                             const float* __restrict__ w_n2e_v,
                             const float* __restrict__ w_e2e,
                             float* __restrict__ Wbig,
                             unsigned short* __restrict__ WTbf) {
    int bidx = blockIdx.x;
    int j = threadIdx.x;
    const float* Ebot = w_e2e + 64 * 64;
    const float* Wv3  = w_n2n_v + 128 * 64;
    if (bidx < 512) {
        int k = bidx >> 2, q = bidx & 3;
        float v = 0.f;
        if (q == 0) {
            v = w_n2n_v[k * 64 + j];
        } else if (q == 1) {
            if (k >= 64) for (int t = 0; t < 64; ++t) v = fmaf(w_n2e_u[(k - 64) * 64 + t], Ebot[t * 64 + j], v);
        } else if (q == 2) {
            for (int t = 0; t < 64; ++t) v = fmaf(w_n2e_v[k * 64 + t], Ebot[t * 64 + j], v);
        } else {
            if (k >= 64) for (int t = 0; t < 64; ++t) v = fmaf(w_n2n_u[(k - 64) * 64 + t], Wv3[t * 64 + j], v);
        }
        Wbig[(size_t)k * 256 + q * 64 + j] = v;
    } else if (bidx < 576) {
        int k = bidx - 512;   // WD row k -> WTbf col-major scatter
        float v = 0.f;
        for (int t = 0; t < 64; ++t) v = fmaf(w_e2n[k * 64 + t], Wv3[t * 64 + j], v);
        WTbf[(64 + j) * 64 + k] = f2bf(v);
    } else {
        int k = bidx - 576;   // W1 row k
        WTbf[j * 64 + k] = f2bf(w_e2e[k * 64 + j]);
    }
}

// ---------------------------------------------------------------------------
// node_pre: out[50000x256] = [S|X] @ Wbig, fp32 register-tiled GEMM.
// q0 -> h_out (+bias_n), q1 -> AX[.,2j] (a), q2 -> bvec, q3 -> AX[.,2j+1] (XC)
// ---------------------------------------------------------------------------
__global__ __launch_bounds__(256) void node_pre(
    const float* __restrict__ S, const float* __restrict__ X,
    const float* __restrict__ Wbig, const float* __restrict__ bias_n,
    float* __restrict__ h_out, float* __restrict__ AX, float* __restrict__ bvec) {
    __shared__ __align__(16) float inT[64 * ET_PAD];
    __shared__ __align__(16) float Wl[64 * 64];
    const int t = threadIdx.x;
    const int m0 = blockIdx.x * 64, q = blockIdx.y, c0 = q * 64;
    const int tx = t & 15, ty = t >> 4;
    float acc[4][4] = {{0.f}};
    for (int h = 0; h < 2; ++h) {
        const float* P = h ? X : S;
        #pragma unroll
        for (int i = 0; i < 16; ++i) {
            int idx = i * 256 + t;
            int ml = idx >> 6, kl = idx & 63;
            int m = m0 + ml;
            inT[kl * ET_PAD + ml] = (m < N_NODES) ? P[(size_t)m * 64 + kl] : 0.f;
        }
        #pragma unroll
        for (int i = 0; i < 16; ++i) {
            int idx = i * 256 + t;
            int kl = idx >> 6, jl = idx & 63;
            Wl[kl * 64 + jl] = Wbig[(size_t)(h * 64 + kl) * 256 + c0 + jl];
        }
        __syncthreads();
        #pragma unroll 4
        for (int kl = 0; kl < 64; ++kl) {
            float4 av = *(const float4*)&inT[kl * ET_PAD + ty * 4];
            float4 wv = *(const float4*)&Wl[kl * 64 + tx * 4];
            float a4[4] = {av.x, av.y, av.z, av.w};
            float w4[4] = {wv.x, wv.y, wv.z, wv.w};
            #pragma unroll
            for (int im = 0; im < 4; ++im)
                #pragma unroll
                for (int ij = 0; ij < 4; ++ij)
                    acc[im][ij] = fmaf(a4[im], w4[ij], acc[im][ij]);
        }
        __syncthreads();
    }
    #pragma unroll
    for (int im = 0; im < 4; ++im) {
        int m = m0 + ty * 4 + im;
        if (m >= N_NODES) continue;
        #pragma unroll
        for (int ij = 0; ij < 4; ++ij) {
            int jl = tx * 4 + ij;
            float v = acc[im][ij];
            if (q == 0)      h_out[(size_t)m * 64 + jl] = v + bias_n[jl];
            else if (q == 1) AX[(size_t)m * 128 + 2 * jl] = v;
            else if (q == 2) bvec[(size_t)m * 64 + jl] = v;
            else             AX[(size_t)m * 128 + 2 * jl + 1] = v;
        }
    }
}

// --------------------------- counting sort by dst ---------------------------
__global__ void hist_k(const int* __restrict__ dst, int* __restrict__ counts) {
    int e = blockIdx.x * 256 + threadIdx.x;
    if (e < N_EDGES) atomicAdd(&counts[dst[e]], 1);
}

__global__ void scan1(const int* __restrict__ counts, int* __restrict__ bsum) {
    __shared__ int s[256];
    int t = threadIdx.x;
    int i = blockIdx.x * 256 + t;
    s[t] = (i < N_NODES) ? counts[i] : 0;
    __syncthreads();
    for (int off = 128; off > 0; off >>= 1) {
        if (t < off) s[t] += s[t + off];
        __syncthreads();
    }
    if (t == 0) bsum[blockIdx.x] = s[0];
}

__global__ void scan2(const int* __restrict__ bsum, int* __restrict__ boff) {
    __shared__ int s[256];
    int t = threadIdx.x;
    int v0 = (t < NB) ? bsum[t] : 0;
    s[t] = v0;
    __syncthreads();
    for (int off = 1; off < 256; off <<= 1) {
        int v = (t >= off) ? s[t - off] : 0;
        __syncthreads();
        s[t] += v;
        __syncthreads();
    }
    if (t < NB) boff[t] = s[t] - v0;  // exclusive
}

__global__ void scan3(const int* __restrict__ counts, const int* __restrict__ boff,
                      int* __restrict__ offsets, int* __restrict__ cursor) {
    __shared__ int s[256];
    int t = threadIdx.x;
    int i = blockIdx.x * 256 + t;
    int v0 = (i < N_NODES) ? counts[i] : 0;
    s[t] = v0;
    __syncthreads();
    for (int off = 1; off < 256; off <<= 1) {
        int v = (t >= off) ? s[t - off] : 0;
        __syncthreads();
        s[t] += v;
        __syncthreads();
    }
    int excl = s[t] - v0 + boff[blockIdx.x];
    if (i < N_NODES) { offsets[i] = excl; cursor[i] = excl; }
    if (i == N_NODES - 1) offsets[N_NODES] = excl + v0;
}

__global__ void scatter_k(const int* __restrict__ src, const int* __restrict__ dst,
                          int* __restrict__ cursor, int4* __restrict__ sEdge) {
    int e = blockIdx.x * 256 + threadIdx.x;
    if (e < N_EDGES) {
        int d = dst[e];
        int p = atomicAdd(&cursor[d], 1);
        sEdge[p] = make_int4(e, src[e], d, 0);
    }
}

// ---------------------------------------------------------------------------
// Edge pass (dst-sorted), bf16 MFMA, ZERO LDS (operand-swapped layout).
// 64 edges/block, 4 waves; each wave owns 16 edges, mirrored across its four
// 16-lane groups (qd = lane>>4). Computes D^T = [W1|WD]^T @ E^T so that lane
// (qd,l15) holds edge l15's output columns n = 16*tt + 4*qd + reg directly.
// NOTE: all cross-lane shuffles are executed UNCONDITIONALLY (full EXEC) —
// ds_bpermute reads from EXEC-masked source lanes are undefined, so the
// predicate shuffles must NOT sit behind a short-circuit lane guard.
// ---------------------------------------------------------------------------
__global__ __launch_bounds__(256) void edge_kernel(
    const float* __restrict__ E, const int4* __restrict__ sEdge,
    const unsigned short* __restrict__ WTbf,
    const float* __restrict__ AX, const float* __restrict__ bvec,
    const float* __restrict__ bias_e,
    float* __restrict__ e_out, float* __restrict__ hpre) {
    const int t = threadIdx.x;
    const int lane = t & 63;
    const int w = t >> 6;
    const int l15 = lane & 15, qd = lane >> 4;

    // this lane's edge (16 per wave; 4-fold broadcast across qd groups)
    int4 ed = sEdge[blockIdx.x * 64 + 16 * w + l15];
    const int perm = ed.x, srcn = ed.y, dstn = ed.z;

    // ---- E gather -> B-fragments: lane loads E[perm][qd*8..+7] and +32 ----
    const float* Erow = E + (size_t)perm * 64 + qd * 8;
    f32x4 e00 = *(const f32x4*)(Erow);
    f32x4 e01 = *(const f32x4*)(Erow + 4);
    f32x4 e10 = *(const f32x4*)(Erow + 32);
    f32x4 e11 = *(const f32x4*)(Erow + 36);

    // ---- AX gather (random src rows) issued early: 8 floats per quad ----
    // chunk u holds [a(c0),xc(c0),a(c1),xc(c1)],[a(c2),xc(c2),a(c3),xc(c3)]
    // for cols c = 16*u + 4*qd + reg
    const float* AXr = AX + (size_t)srcn * 128 + 8 * qd;
    f32x4 ax0[4], ax1[4];
    #pragma unroll
    for (int u = 0; u < 4; ++u) {
        ax0[u] = *(const f32x4*)(AXr + 32 * u);
        ax1[u] = *(const f32x4*)(AXr + 32 * u + 4);
    }

    // in-register bf16 conversion (same f2bf values as the old LDS staging)
    short8 eb0, eb1;
    #pragma unroll
    for (int jj = 0; jj < 4; ++jj) {
        eb0[jj]     = (short)f2bf(e00[jj]);
        eb0[jj + 4] = (short)f2bf(e01[jj]);
        eb1[jj]     = (short)f2bf(e10[jj]);
        eb1[jj + 4] = (short)f2bf(e11[jj]);
    }

    // segmented-scan predicates over the 16-lane edge group (dst sorted).
    // Shuffles hoisted OUT of the short-circuit: all lanes must supply data.
    const int k1 = __shfl_up(dstn, 1, 16);
    const int k2 = __shfl_up(dstn, 2, 16);
    const int k4 = __shfl_up(dstn, 4, 16);
    const int k8 = __shfl_up(dstn, 8, 16);
    const int nd = __shfl_down(dstn, 1, 16);
    const bool p1 = (l15 >= 1) && (k1 == dstn);
    const bool p2 = (l15 >= 2) && (k2 == dstn);
    const bool p4 = (l15 >= 4) && (k4 == dstn);
    const bool p8 = (l15 >= 8) && (k8 == dstn);
    const bool tail = (l15 == 15) || (nd != dstn);

    const unsigned short* Wt = WTbf + l15 * 64 + qd * 8;

    #pragma unroll
    for (int tt = 0; tt < 8; ++tt) {
        short8 wt0 = *(const short8*)(Wt + tt * 16 * 64);
        short8 wt1 = *(const short8*)(Wt + tt * 16 * 64 + 32);
        f32x4 d = {0.f, 0.f, 0.f, 0.f};
        d = __builtin_amdgcn_mfma_f32_16x16x32_bf16(wt0, eb0, d, 0, 0, 0);
        d = __builtin_amdgcn_mfma_f32_16x16x32_bf16(wt1, eb1, d, 0, 0, 0);
        // lane's outputs: edge l15 (row perm/dstn), cols n = 16*tt+4*qd+reg
        if (tt < 4) {
            f32x4 bsv = *(const f32x4*)(bias_e + 16 * tt + 4 * qd);
            f32x4 bvv = *(const f32x4*)(bvec + (size_t)dstn * 64 + 16 * tt + 4 * qd);
            f32x4 o;
            o[0] = d[0] + ax0[tt][0];
            o[1] = d[1] + ax0[tt][2];
            o[2] = d[2] + ax1[tt][0];
            o[3] = d[3] + ax1[tt][2];
            o += bsv + bvv;
            *(f32x4*)(e_out + (size_t)perm * 64 + 16 * tt + 4 * qd) = o;
        } else {
            const int u = tt - 4;
            float v0 = d[0] + ax0[u][1];
            float v1 = d[1] + ax0[u][3];
            float v2 = d[2] + ax1[u][1];
            float v3 = d[3] + ax1[u][3];
            // segmented inclusive scan (keys sorted -> equality check exact);
            // value shuffles are unconditional, only the += is predicated
            { float o0 = __shfl_up(v0, 1, 16), o1 = __shfl_up(v1, 1, 16),
                    o2 = __shfl_up(v2, 1, 16), o3 = __shfl_up(v3, 1, 16);
              if (p1) { v0 += o0; v1 += o1; v2 += o2; v3 += o3; } }
            { float o0 = __shfl_up(v0, 2, 16), o1 = __shfl_up(v1, 2, 16),
                    o2 = __shfl_up(v2, 2, 16), o3 = __shfl_up(v3, 2, 16);
              if (p2) { v0 += o0; v1 += o1; v2 += o2; v3 += o3; } }
            { float o0 = __shfl_up(v0, 4, 16), o1 = __shfl_up(v1, 4, 16),
                    o2 = __shfl_up(v2, 4, 16), o3 = __shfl_up(v3, 4, 16);
              if (p4) { v0 += o0; v1 += o1; v2 += o2; v3 += o3; } }
            { float o0 = __shfl_up(v0, 8, 16), o1 = __shfl_up(v1, 8, 16),
                    o2 = __shfl_up(v2, 8, 16), o3 = __shfl_up(v3, 8, 16);
              if (p8) { v0 += o0; v1 += o1; v2 += o2; v3 += o3; } }
            if (tail) {
                float* hp = hpre + (size_t)dstn * 64 + 16 * u + 4 * qd;
                atomicAdd(hp + 0, v0);
                atomicAdd(hp + 1, v1);
                atomicAdd(hp + 2, v2);
                atomicAdd(hp + 3, v3);
            }
        }
    }
}

// ---------------------------------------------------------------------------
// Final: h_out += hpre / max(deg,1), deg from CSR offsets.
// ---------------------------------------------------------------------------
__global__ void node_final(float* __restrict__ h_out,
                           const float* __restrict__ hpre,
                           const int* __restrict__ offsets) {
    int i = blockIdx.x * blockDim.x + threadIdx.x;
    if (i < N_NODES * 64) {
        int n = i >> 6;
        float deg = (float)(offsets[n + 1] - offsets[n]);
        float r = 1.0f / fmaxf(deg, 1.0f);
        h_out[i] += hpre[i] * r;
    }
}

extern "C" void kernel_launch(void* const* d_in, const int* in_sizes, int n_in,
                              void* d_out, int out_size, void* d_ws, size_t ws_size,
                              hipStream_t stream) {
    const float* S       = (const float*)d_in[0];
    const float* X       = (const float*)d_in[1];
    const float* E       = (const float*)d_in[2];
    const int*   src     = (const int*)  d_in[3];
    const int*   dst     = (const int*)  d_in[4];
    const float* w_n2n_u = (const float*)d_in[5];
    const float* w_n2n_v = (const float*)d_in[6];
    const float* w_e2n   = (const float*)d_in[7];
    const float* bias_n  = (const float*)d_in[8];
    const float* w_n2e_u = (const float*)d_in[9];
    const float* w_n2e_v = (const float*)d_in[10];
    const float* w_e2e   = (const float*)d_in[11];
    const float* bias_e  = (const float*)d_in[12];

    const size_t ND = (size_t)N_NODES * 64;   // 3,200,000

    float* ws = (float*)d_ws;
    float*          hpre    = ws;                                   // 3.2M f (zeroed)
    float*          AX      = ws + ND;                              // 6.4M f
    float*          bvec    = AX + (size_t)N_NODES * 128;           // 3.2M f
    float*          Wbig    = bvec + ND;                            // 32768 f
    unsigned short* WTbf    = (unsigned short*)(Wbig + 128 * 256);  // 8192 u16
    int*            counts  = (int*)(WTbf + 8192);                  // 50000 (zeroed)
    int4*           sEdge   = (int4*)(counts + N_NODES);            // 800000 int4 (16B-aligned)
    int*            offsets = (int*)(sEdge + N_EDGES);              // 50001
    int*            cursor  = offsets + N_NODES + 1;                // 50000
    int*            bsum    = cursor + N_NODES;                     // 200
    int*            boff    = bsum + 200;                           // 200

    float* h_out = (float*)d_out;
    float* e_out = h_out + ND;

    hipMemsetAsync(hpre, 0, ND * sizeof(float), stream);
    hipMemsetAsync(counts, 0, N_NODES * sizeof(int), stream);

    fold_weights<<<640, 64, 0, stream>>>(w_n2n_u, w_n2n_v, w_e2n, w_n2e_u,
                                         w_n2e_v, w_e2e, Wbig, WTbf);

    dim3 npGrid((N_NODES + 63) / 64, 4);
    node_pre<<<npGrid, 256, 0, stream>>>(S, X, Wbig, bias_n, h_out, AX, bvec);

    hist_k <<<(N_EDGES + 255) / 256, 256, 0, stream>>>(dst, counts);
    scan1  <<<NB, 256, 0, stream>>>(counts, bsum);
    scan2  <<<1, 256, 0, stream>>>(bsum, boff);
    scan3  <<<NB, 256, 0, stream>>>(counts, boff, offsets, cursor);
    scatter_k<<<(N_EDGES + 255) / 256, 256, 0, stream>>>(src, dst, cursor, sEdge);

    edge_kernel<<<N_EDGES / 64, 256, 0, stream>>>(
        E, sEdge, WTbf, AX, bvec, bias_e, e_out, hpre);

    node_final<<<(N_NODES * 64 + 255) / 256, 256, 0, stream>>>(h_out, hpre, offsets);
}

// Round 4
// 746.507 us; speedup vs baseline: 1.0012x; 1.0012x over previous
//
#include <hip/hip_runtime.h>

#define N_NODES 50000
#define N_EDGES 800000
#define D 64
#define ET_PAD 68   // node_pre LDS padding
#define NB 196      // ceil(50000/256) scan blocks

typedef __attribute__((ext_vector_type(8))) short short8;
typedef __attribute__((ext_vector_type(4))) float f32x4;

__device__ inline unsigned short f2bf(float f) {
    unsigned u = __float_as_uint(f);
    unsigned r = (u + 0x7FFFu + ((u >> 16) & 1u)) >> 16;
    return (unsigned short)r;
}

// k-slot permutation for the edge MFMA: E-column c -> MFMA k-slot.
// Chosen so that lane (qd,l15)'s four f32x4 E-loads each cover one FULL
// 64B line of the E row:  instr h loads cols 16h+4qd..+3  ->  k-slots
// sig(c) with c = 16h+4q+j:  sig = ((h&2)<<4) + 8q + ((h&1)<<2) + j.
// Bijective (disjoint bit fields); applied to WTbf's k index at fold time;
// exact (pure contraction reorder). Verified: slot kappa = 32*half+8*qd+s
// holds E col c with ksig(c)==kappa for all four (half,s) cases.
__device__ inline int ksig(int c) {
    int h = c >> 4, q = (c >> 2) & 3, j = c & 3;
    return ((h & 2) << 4) + 8 * q + ((h & 1) << 2) + j;
}

// ---------------------------------------------------------------------------
// Weight folding.
// Wbig[128][256] fp32 for node_pre GEMM [S|X]@Wbig:
//   cols 0..63 [Wv1;Wv2]->hbase, 64..127 [0;W_n2e_u@Ebot]->a,
//   128..191 [W_n2e_v@Ebot]->b, 192..255 [0;W_n2n_u@Wv3]->XC
// WTbf[128][64] bf16, B^T layout for the edge MFMA GEMM, k-permuted by ksig:
//   WTbf[n][ksig(k)] = w_e2e[k][n] (n<64), = WD[k][n-64] (n>=64)
//   where WD = W_e2n@Wv3.  Ebot = w_e2e rows 64..127, Wv3 = w_n2n_v rows 128..191.
// ---------------------------------------------------------------------------
__global__ void fold_weights(const float* __restrict__ w_n2n_u,
                             const float* __restrict__ w_n2n_v,
                             const float* __restrict__ w_e2n,
                             const float* __restrict__ w_n2e_u,
                             const float* __restrict__ w_n2e_v,
                             const float* __restrict__ w_e2e,
                             float* __restrict__ Wbig,
                             unsigned short* __restrict__ WTbf) {
    int bidx = blockIdx.x;
    int j = threadIdx.x;
    const float* Ebot = w_e2e + 64 * 64;
    const float* Wv3  = w_n2n_v + 128 * 64;
    if (bidx < 512) {
        int k = bidx >> 2, q = bidx & 3;
        float v = 0.f;
        if (q == 0) {
            v = w_n2n_v[k * 64 + j];
        } else if (q == 1) {
            if (k >= 64) for (int t = 0; t < 64; ++t) v = fmaf(w_n2e_u[(k - 64) * 64 + t], Ebot[t * 64 + j], v);
        } else if (q == 2) {
            for (int t = 0; t < 64; ++t) v = fmaf(w_n2e_v[k * 64 + t], Ebot[t * 64 + j], v);
        } else {
            if (k >= 64) for (int t = 0; t < 64; ++t) v = fmaf(w_n2n_u[(k - 64) * 64 + t], Wv3[t * 64 + j], v);
        }
        Wbig[(size_t)k * 256 + q * 64 + j] = v;
    } else if (bidx < 576) {
        int k = bidx - 512;   // WD row k (E-col) -> WTbf col ksig(k)
        float v = 0.f;
        for (int t = 0; t < 64; ++t) v = fmaf(w_e2n[k * 64 + t], Wv3[t * 64 + j], v);
        WTbf[(64 + j) * 64 + ksig(k)] = f2bf(v);
    } else {
        int k = bidx - 576;   // W1 row k (E-col)
        WTbf[j * 64 + ksig(k)] = f2bf(w_e2e[k * 64 + j]);
    }
}

// ---------------------------------------------------------------------------
// node_pre: out[50000x256] = [S|X] @ Wbig, fp32 register-tiled GEMM.
// q0 -> h_out (+bias_n), q1 -> Aarr (a), q2 -> bvec, q3 -> XCarr (xc)
// (a/xc de-interleaved so the edge kernel's gathers are full-line.)
// ---------------------------------------------------------------------------
__global__ __launch_bounds__(256) void node_pre(
    const float* __restrict__ S, const float* __restrict__ X,
    const float* __restrict__ Wbig, const float* __restrict__ bias_n,
    float* __restrict__ h_out, float* __restrict__ Aarr,
    float* __restrict__ XCarr, float* __restrict__ bvec) {
    __shared__ __align__(16) float inT[64 * ET_PAD];
    __shared__ __align__(16) float Wl[64 * 64];
    const int t = threadIdx.x;
    const int m0 = blockIdx.x * 64, q = blockIdx.y, c0 = q * 64;
    const int tx = t & 15, ty = t >> 4;
    float acc[4][4] = {{0.f}};
    for (int h = 0; h < 2; ++h) {
        const float* P = h ? X : S;
        #pragma unroll
        for (int i = 0; i < 16; ++i) {
            int idx = i * 256 + t;
            int ml = idx >> 6, kl = idx & 63;
            int m = m0 + ml;
            inT[kl * ET_PAD + ml] = (m < N_NODES) ? P[(size_t)m * 64 + kl] : 0.f;
        }
        #pragma unroll
        for (int i = 0; i < 16; ++i) {
            int idx = i * 256 + t;
            int kl = idx >> 6, jl = idx & 63;
            Wl[kl * 64 + jl] = Wbig[(size_t)(h * 64 + kl) * 256 + c0 + jl];
        }
        __syncthreads();
        #pragma unroll 4
        for (int kl = 0; kl < 64; ++kl) {
            float4 av = *(const float4*)&inT[kl * ET_PAD + ty * 4];
            float4 wv = *(const float4*)&Wl[kl * 64 + tx * 4];
            float a4[4] = {av.x, av.y, av.z, av.w};
            float w4[4] = {wv.x, wv.y, wv.z, wv.w};
            #pragma unroll
            for (int im = 0; im < 4; ++im)
                #pragma unroll
                for (int ij = 0; ij < 4; ++ij)
                    acc[im][ij] = fmaf(a4[im], w4[ij], acc[im][ij]);
        }
        __syncthreads();
    }
    #pragma unroll
    for (int im = 0; im < 4; ++im) {
        int m = m0 + ty * 4 + im;
        if (m >= N_NODES) continue;
        #pragma unroll
        for (int ij = 0; ij < 4; ++ij) {
            int jl = tx * 4 + ij;
            float v = acc[im][ij];
            if (q == 0)      h_out[(size_t)m * 64 + jl] = v + bias_n[jl];
            else if (q == 1) Aarr[(size_t)m * 64 + jl] = v;
            else if (q == 2) bvec[(size_t)m * 64 + jl] = v;
            else             XCarr[(size_t)m * 64 + jl] = v;
        }
    }
}

// --------------------------- counting sort by dst ---------------------------
__global__ void hist_k(const int* __restrict__ dst, int* __restrict__ counts) {
    int e = blockIdx.x * 256 + threadIdx.x;
    if (e < N_EDGES) atomicAdd(&counts[dst[e]], 1);
}

__global__ void scan1(const int* __restrict__ counts, int* __restrict__ bsum) {
    __shared__ int s[256];
    int t = threadIdx.x;
    int i = blockIdx.x * 256 + t;
    s[t] = (i < N_NODES) ? counts[i] : 0;
    __syncthreads();
    for (int off = 128; off > 0; off >>= 1) {
        if (t < off) s[t] += s[t + off];
        __syncthreads();
    }
    if (t == 0) bsum[blockIdx.x] = s[0];
}

__global__ void scan2(const int* __restrict__ bsum, int* __restrict__ boff) {
    __shared__ int s[256];
    int t = threadIdx.x;
    int v0 = (t < NB) ? bsum[t] : 0;
    s[t] = v0;
    __syncthreads();
    for (int off = 1; off < 256; off <<= 1) {
        int v = (t >= off) ? s[t - off] : 0;
        __syncthreads();
        s[t] += v;
        __syncthreads();
    }
    if (t < NB) boff[t] = s[t] - v0;  // exclusive
}

__global__ void scan3(const int* __restrict__ counts, const int* __restrict__ boff,
                      int* __restrict__ offsets, int* __restrict__ cursor) {
    __shared__ int s[256];
    int t = threadIdx.x;
    int i = blockIdx.x * 256 + t;
    int v0 = (i < N_NODES) ? counts[i] : 0;
    s[t] = v0;
    __syncthreads();
    for (int off = 1; off < 256; off <<= 1) {
        int v = (t >= off) ? s[t - off] : 0;
        __syncthreads();
        s[t] += v;
        __syncthreads();
    }
    int excl = s[t] - v0 + boff[blockIdx.x];
    if (i < N_NODES) { offsets[i] = excl; cursor[i] = excl; }
    if (i == N_NODES - 1) offsets[N_NODES] = excl + v0;
}

__global__ void scatter_k(const int* __restrict__ src, const int* __restrict__ dst,
                          int* __restrict__ cursor, int4* __restrict__ sEdge) {
    int e = blockIdx.x * 256 + threadIdx.x;
    if (e < N_EDGES) {
        int d = dst[e];
        int p = atomicAdd(&cursor[d], 1);
        sEdge[p] = make_int4(e, src[e], d, 0);
    }
}

// ---------------------------------------------------------------------------
// Edge pass (dst-sorted), bf16 MFMA, zero LDS, FULL-LINE gathers.
// Lane (qd,l15): every global load instruction covers complete 64B lines —
// E via the ksig k-permutation (4 instrs, one line/row each), a/xc/bvec via
// de-interleaved [N][64] arrays (instr u covers line u of 16 rows).
// ~370 memory transactions/wave vs ~560 before (transaction-rate bound).
// All cross-lane shuffles executed with full EXEC (bpermute masked-source
// is undefined — Round-1 lesson).
// ---------------------------------------------------------------------------
__global__ __launch_bounds__(256) void edge_kernel(
    const float* __restrict__ E, const int4* __restrict__ sEdge,
    const unsigned short* __restrict__ WTbf,
    const float* __restrict__ Aarr, const float* __restrict__ XCarr,
    const float* __restrict__ bvec, const float* __restrict__ bias_e,
    float* __restrict__ e_out, float* __restrict__ hpre) {
    const int t = threadIdx.x;
    const int lane = t & 63;
    const int w = t >> 6;
    const int l15 = lane & 15, qd = lane >> 4;

    // this lane's edge (16 per wave; 4-fold broadcast across qd groups)
    int4 ed = sEdge[blockIdx.x * 64 + 16 * w + l15];
    const int perm = ed.x, srcn = ed.y, dstn = ed.z;

    // ---- E gather: instr h reads cols 16h+4qd..+3 -> line h of the row ----
    const float* Erow = E + (size_t)perm * 64 + 4 * qd;
    f32x4 L0 = *(const f32x4*)(Erow);
    f32x4 L1 = *(const f32x4*)(Erow + 16);
    f32x4 L2 = *(const f32x4*)(Erow + 32);
    f32x4 L3 = *(const f32x4*)(Erow + 48);

    // ---- a / xc gathers (random src rows), full-line per instruction ----
    const float* Ar = Aarr  + (size_t)srcn * 64 + 4 * qd;
    const float* Xr = XCarr + (size_t)srcn * 64 + 4 * qd;
    f32x4 av[4], xv[4];
    #pragma unroll
    for (int u = 0; u < 4; ++u) {
        av[u] = *(const f32x4*)(Ar + 16 * u);
        xv[u] = *(const f32x4*)(Xr + 16 * u);
    }

    // in-register bf16 conversion; k-slots per ksig (matches WTbf folding)
    short8 eb0, eb1;
    #pragma unroll
    for (int jj = 0; jj < 4; ++jj) {
        eb0[jj]     = (short)f2bf(L0[jj]);
        eb0[jj + 4] = (short)f2bf(L1[jj]);
        eb1[jj]     = (short)f2bf(L2[jj]);
        eb1[jj + 4] = (short)f2bf(L3[jj]);
    }

    // segmented-scan predicates over the 16-lane edge group (dst sorted).
    // Shuffles hoisted OUT of the short-circuit: all lanes must supply data.
    const int k1 = __shfl_up(dstn, 1, 16);
    const int k2 = __shfl_up(dstn, 2, 16);
    const int k4 = __shfl_up(dstn, 4, 16);
    const int k8 = __shfl_up(dstn, 8, 16);
    const int nd = __shfl_down(dstn, 1, 16);
    const bool p1 = (l15 >= 1) && (k1 == dstn);
    const bool p2 = (l15 >= 2) && (k2 == dstn);
    const bool p4 = (l15 >= 4) && (k4 == dstn);
    const bool p8 = (l15 >= 8) && (k8 == dstn);
    const bool tail = (l15 == 15) || (nd != dstn);

    const unsigned short* Wt = WTbf + l15 * 64 + qd * 8;
    const float* Br = bvec + (size_t)dstn * 64 + 4 * qd;

    #pragma unroll
    for (int tt = 0; tt < 8; ++tt) {
        short8 wt0 = *(const short8*)(Wt + tt * 16 * 64);
        short8 wt1 = *(const short8*)(Wt + tt * 16 * 64 + 32);
        f32x4 d = {0.f, 0.f, 0.f, 0.f};
        d = __builtin_amdgcn_mfma_f32_16x16x32_bf16(wt0, eb0, d, 0, 0, 0);
        d = __builtin_amdgcn_mfma_f32_16x16x32_bf16(wt1, eb1, d, 0, 0, 0);
        // lane's outputs: edge l15 (row perm/dstn), cols n = 16*tt+4*qd+reg
        if (tt < 4) {
            f32x4 bsv = *(const f32x4*)(bias_e + 16 * tt + 4 * qd);
            f32x4 bvv = *(const f32x4*)(Br + 16 * tt);
            f32x4 o = d + av[tt] + bsv + bvv;
            *(f32x4*)(e_out + (size_t)perm * 64 + 16 * tt + 4 * qd) = o;
        } else {
            const int u = tt - 4;
            float v0 = d[0] + xv[u][0];
            float v1 = d[1] + xv[u][1];
            float v2 = d[2] + xv[u][2];
            float v3 = d[3] + xv[u][3];
            // segmented inclusive scan (keys sorted -> equality check exact);
            // value shuffles are unconditional, only the += is predicated
            { float o0 = __shfl_up(v0, 1, 16), o1 = __shfl_up(v1, 1, 16),
                    o2 = __shfl_up(v2, 1, 16), o3 = __shfl_up(v3, 1, 16);
              if (p1) { v0 += o0; v1 += o1; v2 += o2; v3 += o3; } }
            { float o0 = __shfl_up(v0, 2, 16), o1 = __shfl_up(v1, 2, 16),
                    o2 = __shfl_up(v2, 2, 16), o3 = __shfl_up(v3, 2, 16);
              if (p2) { v0 += o0; v1 += o1; v2 += o2; v3 += o3; } }
            { float o0 = __shfl_up(v0, 4, 16), o1 = __shfl_up(v1, 4, 16),
                    o2 = __shfl_up(v2, 4, 16), o3 = __shfl_up(v3, 4, 16);
              if (p4) { v0 += o0; v1 += o1; v2 += o2; v3 += o3; } }
            { float o0 = __shfl_up(v0, 8, 16), o1 = __shfl_up(v1, 8, 16),
                    o2 = __shfl_up(v2, 8, 16), o3 = __shfl_up(v3, 8, 16);
              if (p8) { v0 += o0; v1 += o1; v2 += o2; v3 += o3; } }
            if (tail) {
                float* hp = hpre + (size_t)dstn * 64 + 16 * u + 4 * qd;
                atomicAdd(hp + 0, v0);
                atomicAdd(hp + 1, v1);
                atomicAdd(hp + 2, v2);
                atomicAdd(hp + 3, v3);
            }
        }
    }
}

// ---------------------------------------------------------------------------
// Final: h_out += hpre / max(deg,1), deg from CSR offsets.
// ---------------------------------------------------------------------------
__global__ void node_final(float* __restrict__ h_out,
                           const float* __restrict__ hpre,
                           const int* __restrict__ offsets) {
    int i = blockIdx.x * blockDim.x + threadIdx.x;
    if (i < N_NODES * 64) {
        int n = i >> 6;
        float deg = (float)(offsets[n + 1] - offsets[n]);
        float r = 1.0f / fmaxf(deg, 1.0f);
        h_out[i] += hpre[i] * r;
    }
}

extern "C" void kernel_launch(void* const* d_in, const int* in_sizes, int n_in,
                              void* d_out, int out_size, void* d_ws, size_t ws_size,
                              hipStream_t stream) {
    const float* S       = (const float*)d_in[0];
    const float* X       = (const float*)d_in[1];
    const float* E       = (const float*)d_in[2];
    const int*   src     = (const int*)  d_in[3];
    const int*   dst     = (const int*)  d_in[4];
    const float* w_n2n_u = (const float*)d_in[5];
    const float* w_n2n_v = (const float*)d_in[6];
    const float* w_e2n   = (const float*)d_in[7];
    const float* bias_n  = (const float*)d_in[8];
    const float* w_n2e_u = (const float*)d_in[9];
    const float* w_n2e_v = (const float*)d_in[10];
    const float* w_e2e   = (const float*)d_in[11];
    const float* bias_e  = (const float*)d_in[12];

    const size_t ND = (size_t)N_NODES * 64;   // 3,200,000

    float* ws = (float*)d_ws;
    float*          hpre    = ws;                                   // 3.2M f (zeroed)
    float*          Aarr    = ws + ND;                              // 3.2M f
    float*          XCarr   = Aarr + ND;                            // 3.2M f
    float*          bvec    = XCarr + ND;                           // 3.2M f
    float*          Wbig    = bvec + ND;                            // 32768 f
    unsigned short* WTbf    = (unsigned short*)(Wbig + 128 * 256);  // 8192 u16
    int*            counts  = (int*)(WTbf + 8192);                  // 50000 (zeroed)
    int4*           sEdge   = (int4*)(counts + N_NODES);            // 800000 int4 (16B-aligned)
    int*            offsets = (int*)(sEdge + N_EDGES);              // 50001
    int*            cursor  = offsets + N_NODES + 1;                // 50000
    int*            bsum    = cursor + N_NODES;                     // 200
    int*            boff    = bsum + 200;                           // 200

    float* h_out = (float*)d_out;
    float* e_out = h_out + ND;

    hipMemsetAsync(hpre, 0, ND * sizeof(float), stream);
    hipMemsetAsync(counts, 0, N_NODES * sizeof(int), stream);

    fold_weights<<<640, 64, 0, stream>>>(w_n2n_u, w_n2n_v, w_e2n, w_n2e_u,
                                         w_n2e_v, w_e2e, Wbig, WTbf);

    dim3 npGrid((N_NODES + 63) / 64, 4);
    node_pre<<<npGrid, 256, 0, stream>>>(S, X, Wbig, bias_n, h_out, Aarr, XCarr, bvec);

    hist_k <<<(N_EDGES + 255) / 256, 256, 0, stream>>>(dst, counts);
    scan1  <<<NB, 256, 0, stream>>>(counts, bsum);
    scan2  <<<1, 256, 0, stream>>>(bsum, boff);
    scan3  <<<NB, 256, 0, stream>>>(counts, boff, offsets, cursor);
    scatter_k<<<(N_EDGES + 255) / 256, 256, 0, stream>>>(src, dst, cursor, sEdge);

    edge_kernel<<<N_EDGES / 64, 256, 0, stream>>>(
        E, sEdge, WTbf, Aarr, XCarr, bvec, bias_e, e_out, hpre);

    node_final<<<(N_NODES * 64 + 255) / 256, 256, 0, stream>>>(h_out, hpre, offsets);
}